// Round 10
// baseline (207.844 us; speedup 1.0000x reference)
//
#include <hip/hip_runtime.h>
#include <hip/hip_bf16.h>

// Problem constants
#define B_ 2
#define S_ 2048
#define DM_ 1024
#define TD_ 1024
#define H_ 16
#define HD_ 64

using bf16 = __hip_bfloat16;
typedef __attribute__((ext_vector_type(8))) short s8v;   // 8 bf16 = one MFMA A/B frag
typedef __attribute__((ext_vector_type(4))) float f4v;   // MFMA C/D frag

__device__ __forceinline__ f4v mfma_bf16(s8v a, s8v b, f4v c) {
    return __builtin_amdgcn_mfma_f32_16x16x32_bf16(a, b, c, 0, 0, 0);
}

// HW packed fp32x2 -> bf16x2 (RNE), single VOP3 instr on CDNA3/4
__device__ __forceinline__ unsigned cvt_pk_bf16(float a, float b) {
    unsigned r;
    asm("v_cvt_pk_bf16_f32 %0, %1, %2" : "=v"(r) : "v"(a), "v"(b));
    return r;
}
__device__ __forceinline__ int2 pack4bf(float a, float b, float c, float d) {
    int2 r;
    r.x = (int)cvt_pk_bf16(a, b);
    r.y = (int)cvt_pk_bf16(c, d);
    return r;
}

// cos_q[0] == 1.0 exactly: fp32 word = 0x3F800000 (low16==0); bf16 pair != 0 low16.
__device__ __forceinline__ bool detect_f32(const unsigned int* __restrict__ cosw) {
    return (cosw[0] & 0xFFFFu) == 0u;
}

__device__ __forceinline__ float ld_f(const void* p, int idx, bool f32) {
    return f32 ? ((const float*)p)[idx]
               : __bfloat162float(((const bf16*)p)[idx]);
}

// async global -> LDS, 16 B per lane (HW: dst = wave-uniform base + lane*16)
__device__ __forceinline__ void gload_lds16(const bf16* g, void* l) {
    __builtin_amdgcn_global_load_lds(
        (const __attribute__((address_space(1))) unsigned int*)(const void*)g,
        (__attribute__((address_space(3))) unsigned int*)l,
        16, 0, 0);
}

#define NQ_  (B_ * S_ * DM_)
#define NWI_ (3 * TD_ * DM_)
#define NWO_ (DM_ * TD_)
#define NCVT_BLOCKS ((NQ_ + NWI_ + NWO_) / 2048)   // 4096

// ---------------------------------------------------------------------------
// Fused prep: blocks [0,4096) convert (query|W_in|W_out) -> bf16;
// blocks 4096..4097 compute lengths[b] from the mask (4-way storage detect).
// ---------------------------------------------------------------------------
__global__ __launch_bounds__(256)
void prep_all(const void* __restrict__ q, const void* __restrict__ wi,
              const void* __restrict__ wo, bf16* __restrict__ dst,
              const void* __restrict__ mask, int* __restrict__ lengths,
              const unsigned int* __restrict__ cosw) {
    const int bid = blockIdx.x;
    if (bid < NCVT_BLOCKS) {
        const bool f32 = detect_f32(cosw);
        int i = (bid * 256 + threadIdx.x) * 8;
        const void* src; int off;
        if (i < NQ_)              { src = q;  off = i; }
        else if (i < NQ_ + NWI_)  { src = wi; off = i - NQ_; }
        else                      { src = wo; off = i - NQ_ - NWI_; }
        if (f32) {
            const float* p = (const float*)src + off;
            float4 x = *reinterpret_cast<const float4*>(p);
            float4 y = *reinterpret_cast<const float4*>(p + 4);
            union { unsigned u[4]; int4 v; } t;
            t.u[0] = cvt_pk_bf16(x.x, x.y);
            t.u[1] = cvt_pk_bf16(x.z, x.w);
            t.u[2] = cvt_pk_bf16(y.x, y.y);
            t.u[3] = cvt_pk_bf16(y.z, y.w);
            *reinterpret_cast<int4*>(dst + i) = t.v;
        } else {
            *reinterpret_cast<int4*>(dst + i) =
                *reinterpret_cast<const int4*>((const bf16*)src + off);
        }
        return;
    }
    // lengths path
    int b = bid - NCVT_BLOCKS;
    unsigned int w0 = ((const unsigned int*)mask)[0];
    int enc;                 // 0=i32, 1=u8, 2=bf16, 3=f32
    if (w0 == 1u) enc = 0;
    else if (w0 == 0x01010101u) enc = 1;
    else if (w0 == 0x3F803F80u) enc = 2;
    else enc = 3;
    int cnt = 0;
    for (int s = threadIdx.x; s < S_; s += 256) {
        int i = b * S_ + s;
        bool v;
        if (enc == 0)      v = ((const int*)mask)[i] != 0;
        else if (enc == 1) v = ((const unsigned char*)mask)[i] != 0;
        else if (enc == 2) v = ((const unsigned short*)mask)[i] != 0;
        else               v = ((const float*)mask)[i] != 0.f;
        cnt += v ? 1 : 0;
    }
    __shared__ int red[256];
    red[threadIdx.x] = cnt;
    __syncthreads();
    for (int off = 128; off > 0; off >>= 1) {
        if (threadIdx.x < off) red[threadIdx.x] += red[threadIdx.x + off];
        __syncthreads();
    }
    if (threadIdx.x == 0) lengths[b] = red[0];
}

// ---------------------------------------------------------------------------
// NT GEMM: C[M][N] = A[M][K]*Bm[N][K]^T. bf16 in, fp32 acc. BK=64,
// global_load_lds width-16, XOR-swizzled LDS. MFMA operands SWAPPED
// (D = Bm_tile * A_tile) so each lane owns 4 consecutive n -> b64/b128 stores.
// c_dyn: 1 -> write detected dtype (fp32 if inputs fp32), 0 -> bf16.
// ---------------------------------------------------------------------------
__global__ __launch_bounds__(256)
void gemm_nt(const bf16* __restrict__ A, const bf16* __restrict__ Bm,
             void* __restrict__ C, int M, int N, int K,
             int c_dyn, const unsigned int* __restrict__ cosw) {
    __shared__ bf16 lds_a[128 * 64];   // 16 KB, [row][chunk^(row&7)]
    __shared__ bf16 lds_b[128 * 64];

    const bool cf32 = c_dyn && detect_f32(cosw);

    const int t = threadIdx.x;
    const int wave = t >> 6, lane = t & 63;
    const int quad = lane >> 4, l16 = lane & 15;
    const int wm = wave >> 1, wn = wave & 1;
    const int m0 = blockIdx.y * 128, n0 = blockIdx.x * 128;
    const int wuni = __builtin_amdgcn_readfirstlane(wave);   // wave-uniform

    f4v acc[4][4];
    #pragma unroll
    for (int i = 0; i < 4; i++)
        #pragma unroll
        for (int j = 0; j < 4; j++)
            acc[i][j] = f4v{0.f, 0.f, 0.f, 0.f};

    for (int k0 = 0; k0 < K; k0 += 64) {
        __syncthreads();                 // prior reads done before restage
        #pragma unroll
        for (int i = 0; i < 4; i++) {
            int ci = i * 256 + t;        // chunk 0..1023 (16B each)
            int row = ci >> 3;
            int csrc = (ci & 7) ^ (row & 7);
            gload_lds16(A + (size_t)(m0 + row) * K + k0 + csrc * 8,
                        (char*)lds_a + i * 4096 + wuni * 1024);
            gload_lds16(Bm + (size_t)(n0 + row) * K + k0 + csrc * 8,
                        (char*)lds_b + i * 4096 + wuni * 1024);
        }
        __syncthreads();                 // drains vmcnt -> staged data visible

        #pragma unroll
        for (int kk = 0; kk < 2; kk++) {
            s8v afr[4], bfr[4];
            #pragma unroll
            for (int mb = 0; mb < 4; mb++) {
                int r = wm * 64 + mb * 16 + l16;
                int ch = (kk * 4 + quad) ^ (l16 & 7);
                afr[mb] = *reinterpret_cast<const s8v*>(&lds_a[r * 64 + ch * 8]);
            }
            #pragma unroll
            for (int nb = 0; nb < 4; nb++) {
                int r = wn * 64 + nb * 16 + l16;
                int ch = (kk * 4 + quad) ^ (l16 & 7);
                bfr[nb] = *reinterpret_cast<const s8v*>(&lds_b[r * 64 + ch * 8]);
            }
            // swapped: D[i=n-in-16][j=m-in-16], lane j=l16, regs i=quad*4+rr
            #pragma unroll
            for (int mb = 0; mb < 4; mb++)
                #pragma unroll
                for (int nb = 0; nb < 4; nb++)
                    acc[mb][nb] = mfma_bf16(bfr[nb], afr[mb], acc[mb][nb]);
        }
    }

    // epilogue: m = m0+wm*64+mb*16+l16 (per lane), n = n0+wn*64+nb*16+quad*4+rr
    #pragma unroll
    for (int mb = 0; mb < 4; mb++) {
        int m = m0 + wm * 64 + mb * 16 + l16;
        #pragma unroll
        for (int nb = 0; nb < 4; nb++) {
            int n = n0 + wn * 64 + nb * 16 + quad * 4;
            f4v v = acc[mb][nb];
            if (cf32) {
                *reinterpret_cast<f4v*>(&((float*)C)[(size_t)m * N + n]) = v;
            } else {
                *reinterpret_cast<int2*>(&((bf16*)C)[(size_t)m * N + n]) =
                    pack4bf(v[0], v[1], v[2], v[3]);
            }
        }
    }
}

// ---------------------------------------------------------------------------
// Fused RoPE + V-transpose (same as round 9).
// ---------------------------------------------------------------------------
__global__ __launch_bounds__(256)
void rope_vt(const bf16* __restrict__ qkv,
             const void* __restrict__ sin_t, const void* __restrict__ cos_t,
             bf16* __restrict__ Qh, bf16* __restrict__ Kt, bf16* __restrict__ Vt) {
    __shared__ bf16 tile[64 * 72];     // used by vt path only
    const int bid = blockIdx.x;
    if (bid < 16384) {
        const bool f32 = detect_f32((const unsigned int*)cos_t);
        int idx = bid * 256 + threadIdx.x;   // B*S*H*HD = 2^22
        int d = idx & 63;
        int h = (idx >> 6) & 15;
        int s = (idx >> 10) & 2047;
        int b = idx >> 21;
        size_t row = (size_t)(b * S_ + s) * 3072;
        int col  = h * 64 + d;
        int colp = h * 64 + ((d + 32) & 63);
        float sgn = (d < 32) ? -1.f : 1.f;
        float cs = ld_f(cos_t, s * 64 + d, f32);
        float sn = ld_f(sin_t, s * 64 + d, f32);
        float q  = __bfloat162float(qkv[row + col]);
        float qp = __bfloat162float(qkv[row + colp]);
        float k  = __bfloat162float(qkv[row + 1024 + col]);
        float kp = __bfloat162float(qkv[row + 1024 + colp]);
        Qh[((size_t)((b * H_ + h) * S_ + s)) * 64 + d] =
            __float2bfloat16((q * cs + sgn * qp * sn) * 0.180336880f);  // 1/8*log2e
        size_t ktile = ((size_t)(b * H_ + h) * 32 + (s >> 6)) * 4096;
        int dp = ((((d >> 3) ^ (s & 7)) << 3) | (d & 7));
        Kt[ktile + (s & 63) * 64 + dp] = __float2bfloat16(k * cs + sgn * kp * sn);
        return;
    }
    // V-transpose path
    const int vid = bid - 16384;       // 0..1023
    const int sb = vid & 31, h = (vid >> 5) & 15, b = vid >> 9;
    const int t = threadIdx.x;
    #pragma unroll
    for (int i = 0; i < 2; i++) {
        int id = i * 256 + t;          // 0..511
        int row = id >> 3, c = id & 7;
        *reinterpret_cast<int4*>(&tile[row * 72 + c * 8]) =
            *reinterpret_cast<const int4*>(
                qkv + (size_t)(b * S_ + sb * 64 + row) * 3072 + 2048 + h * 64 + c * 8);
    }
    __syncthreads();
    const size_t tb = ((size_t)(b * H_ + h) * 32 + sb) * 4096;
    #pragma unroll
    for (int i = 0; i < 2; i++) {
        int id = i * 256 + t;
        int d = id >> 3, kc = id & 7;  // kc = 8-key chunk
        union { short s[8]; int4 v; } u;
        #pragma unroll
        for (int e = 0; e < 8; e++)
            u.s[e] = reinterpret_cast<const short*>(tile)[(kc * 8 + e) * 72 + d];
        *reinterpret_cast<int4*>(Vt + tb + d * 64 + ((kc ^ (d & 7)) * 8)) = u.v;
    }
}

// ---------------------------------------------------------------------------
// Flash attention v7: MERGED concurrent causal pair. Block handles q-tiles
// A = qb p and B = qb 31-p in ONE kt loop (kt = 0..31-p); K/V fragments are
// read from LDS once and feed both q-sets (A active while kt <= p).
// Tile-iters: 16.9k -> 12.5k; staging -26%; frag-reads/MFMA halved in overlap.
// Balance: bid and bid+256 (same XCD via &7, round-robin -> same CU) carry
// complementary p (g vs 15-g): per-CU iter sum = 49 uniform.
// Depth-2 pipeline as before: stage V[kt]+K[kt+1]; S[kt]; exp/PV[kt-1]; 1 barrier.
// ---------------------------------------------------------------------------
__global__ __launch_bounds__(256)
void attn_fused(const bf16* __restrict__ Qh, const bf16* __restrict__ Kt,
                const bf16* __restrict__ Vt, const int* __restrict__ lengths,
                bf16* __restrict__ out) {
    __shared__ bf16 k_buf[2 * 4096];    // K tiles  [row(key)][chunk^(key&7)]
    __shared__ bf16 v_buf[2 * 4096];    // Vt tiles [row(d)][keychunk^(d&7)]
    __shared__ bf16 lds_pA[4 * 16 * 72];// per-wave P tile, set A
    __shared__ bf16 lds_pB[4 * 16 * 72];// per-wave P tile, set B

    const int t = threadIdx.x, wave = t >> 6, lane = t & 63;
    const int quad = lane >> 4, l16 = lane & 15;
    // decode: xcd = bid&7; slot = bid>>3 (0..63); s5 = slot&31; hi = slot>>5
    // bh = xcd*4 + (s5&3); p = hi ? 15-(s5>>2) : (s5>>2)
    const int bid = blockIdx.x;
    const int slot = bid >> 3;
    const int s5 = slot & 31, hi = slot >> 5;
    const int bh = (bid & 7) * 4 + (s5 & 3);
    const int g = s5 >> 2;
    const int p = hi ? (15 - g) : g;
    const int b = bh >> 4, h = bh & 15;

    const size_t hb = (size_t)bh * S_ * 64;          // Qh base
    const bf16* Ktp = Kt + (size_t)bh * 32 * 4096;   // tile array base
    const bf16* Vtp = Vt + (size_t)bh * 32 * 4096;
    const int wuni = __builtin_amdgcn_readfirstlane(wave);
    int len_raw = lengths[b];
    const int len_b = len_raw < 1 ? 1 : (len_raw > S_ ? S_ : len_raw);
    const int nkt_len = (len_b + 63) >> 6;

    const int qbA = p, qbB = 31 - p;
    const int qrowA = qbA * 64 + wave * 16 + l16;
    const int qrowB = qbB * 64 + wave * 16 + l16;
    const int kmaxA = (qrowA < len_b - 1) ? qrowA : (len_b - 1);
    const int kmaxB = (qrowB < len_b - 1) ? qrowB : (len_b - 1);

    s8v qfA[2], qfB[2];
    {
        const bf16* qp_ = Qh + hb + (size_t)qrowA * 64 + quad * 8;
        qfA[0] = *reinterpret_cast<const s8v*>(qp_);
        qfA[1] = *reinterpret_cast<const s8v*>(qp_ + 32);
        const bf16* qp2 = Qh + hb + (size_t)qrowB * 64 + quad * 8;
        qfB[0] = *reinterpret_cast<const s8v*>(qp2);
        qfB[1] = *reinterpret_cast<const s8v*>(qp2 + 32);
    }

    f4v oA[4], oB[4];
    #pragma unroll
    for (int a = 0; a < 4; a++) { oA[a] = f4v{0.f,0.f,0.f,0.f}; oB[a] = f4v{0.f,0.f,0.f,0.f}; }
    float lA = 0.f, lB = 0.f;

    const int nkt = (qbB + 1) < nkt_len ? (qbB + 1) : nkt_len;  // B's span >= A's

    f4v sA[4], sB[4];   // pipelined S^T of previous tile

    // exp/pack/PV for tile tau (actA: set A participated at tau)
    auto process_prev = [&](int tau, bool actA, const bf16* vb) {
        const int pbase = tau * 64;
        const bool lenTail = (pbase + 64 > len_b);
        // --- set B exp/pack (B active at every tau in loop) ---
        {
            const bool tail = (tau == qbB) || lenTail;
            #pragma unroll
            for (int a = 0; a < 4; a++) {
                float e0[4];
                #pragma unroll
                for (int r = 0; r < 4; r++) {
                    float e = __builtin_amdgcn_exp2f(sB[a][r]);
                    if (tail) {
                        int key = pbase + a * 16 + quad * 4 + r;
                        e = (key <= kmaxB) ? e : 0.f;
                    }
                    e0[r] = e; lB += e;
                }
                *reinterpret_cast<int2*>(
                    &lds_pB[(wave * 16 + l16) * 72 + a * 16 + quad * 4]) =
                    pack4bf(e0[0], e0[1], e0[2], e0[3]);
            }
        }
        // --- set A exp/pack ---
        if (actA) {
            const bool tail = (tau == qbA) || lenTail;
            #pragma unroll
            for (int a = 0; a < 4; a++) {
                float e0[4];
                #pragma unroll
                for (int r = 0; r < 4; r++) {
                    float e = __builtin_amdgcn_exp2f(sA[a][r]);
                    if (tail) {
                        int key = pbase + a * 16 + quad * 4 + r;
                        e = (key <= kmaxA) ? e : 0.f;
                    }
                    e0[r] = e; lA += e;
                }
                *reinterpret_cast<int2*>(
                    &lds_pA[(wave * 16 + l16) * 72 + a * 16 + quad * 4]) =
                    pack4bf(e0[0], e0[1], e0[2], e0[3]);
            }
        }
        // wave-local: P writes -> P reads (lds_p regions are per-wave)
        asm volatile("s_waitcnt lgkmcnt(0)" ::: "memory");
        // --- PV: vf read once, feeds both sets ---
        #pragma unroll
        for (int kk = 0; kk < 2; kk++) {
            s8v pfB = *reinterpret_cast<const s8v*>(
                &lds_pB[(wave * 16 + l16) * 72 + kk * 32 + quad * 8]);
            s8v pfA;
            if (actA) pfA = *reinterpret_cast<const s8v*>(
                &lds_pA[(wave * 16 + l16) * 72 + kk * 32 + quad * 8]);
            #pragma unroll
            for (int a = 0; a < 4; a++) {
                int ch = (kk * 4 + quad) ^ (l16 & 7);
                s8v vf = *reinterpret_cast<const s8v*>(
                    &vb[(a * 16 + l16) * 64 + ch * 8]);
                oB[a] = mfma_bf16(vf, pfB, oB[a]);
                if (actA) oA[a] = mfma_bf16(vf, pfA, oA[a]);
            }
        }
    };

    // prologue: stage K[0]
    #pragma unroll
    for (int i = 0; i < 2; i++) {
        int ci = i * 256 + t;
        gload_lds16(Ktp + ci * 8, (char*)k_buf + i * 4096 + wuni * 1024);
    }
    __syncthreads();   // K[0] resident (drains vmcnt)

    for (int kt = 0; kt < nkt; kt++) {
        const int cur = kt & 1;
        // stage V[kt] -> vbuf[cur] (one tile behind K)
        {
            const bf16* vst = Vtp + (size_t)kt * 4096;
            #pragma unroll
            for (int i = 0; i < 2; i++) {
                int ci = i * 256 + t;
                gload_lds16(vst + ci * 8,
                            (char*)v_buf + cur * 8192 + i * 4096 + wuni * 1024);
            }
        }
        // stage K[kt+1] -> kbuf[cur^1]
        if (kt + 1 < nkt) {
            const bf16* kst = Ktp + (size_t)(kt + 1) * 4096;
            #pragma unroll
            for (int i = 0; i < 2; i++) {
                int ci = i * 256 + t;
                gload_lds16(kst + ci * 8,
                            (char*)k_buf + (cur ^ 1) * 8192 + i * 4096 + wuni * 1024);
            }
        }

        // S^T[kt] for both sets: kf read once each (kk,a)
        const bf16* kb = k_buf + cur * 4096;
        const bool actA_now = (kt <= p);
        f4v s_nA[4], s_nB[4];
        #pragma unroll
        for (int a = 0; a < 4; a++) { s_nA[a] = f4v{0.f,0.f,0.f,0.f}; s_nB[a] = f4v{0.f,0.f,0.f,0.f}; }
        #pragma unroll
        for (int kk = 0; kk < 2; kk++) {
            #pragma unroll
            for (int a = 0; a < 4; a++) {
                int ch = (kk * 4 + quad) ^ (l16 & 7);
                s8v kf = *reinterpret_cast<const s8v*>(
                    &kb[(a * 16 + l16) * 64 + ch * 8]);
                s_nB[a] = mfma_bf16(kf, qfB[kk], s_nB[a]);
                if (actA_now) s_nA[a] = mfma_bf16(kf, qfA[kk], s_nA[a]);
            }
        }

        // overlap: previous tile's exp/pack/PV under this tile's S-MFMA
        if (kt > 0) process_prev(kt - 1, (kt - 1) <= p, v_buf + ((kt - 1) & 1) * 4096);

        #pragma unroll
        for (int a = 0; a < 4; a++) { sB[a] = s_nB[a]; if (actA_now) sA[a] = s_nA[a]; }

        __syncthreads();   // V[kt], K[kt+1] staged; LDS reads done before reuse
    }
    // drain: last tile (A participates if its span reaches nkt-1)
    process_prev(nkt - 1, (nkt - 1) <= p, v_buf + ((nkt - 1) & 1) * 4096);

    // reduce l across the 4 quads sharing each q-row, then b64 epilogues
    lA += __shfl_xor(lA, 16); lA += __shfl_xor(lA, 32);
    lB += __shfl_xor(lB, 16); lB += __shfl_xor(lB, 32);
    float invA = 1.f / lA, invB = 1.f / lB;
    size_t orowA = ((size_t)(b * S_ + qrowA)) * TD_ + h * 64;
    size_t orowB = ((size_t)(b * S_ + qrowB)) * TD_ + h * 64;
    #pragma unroll
    for (int a = 0; a < 4; a++) {
        *reinterpret_cast<int2*>(&out[orowA + a * 16 + quad * 4]) =
            pack4bf(oA[a][0] * invA, oA[a][1] * invA, oA[a][2] * invA, oA[a][3] * invA);
        *reinterpret_cast<int2*>(&out[orowB + a * 16 + quad * 4]) =
            pack4bf(oB[a][0] * invB, oB[a][1] * invB, oB[a][2] * invB, oB[a][3] * invB);
    }
}

// ---------------------------------------------------------------------------
extern "C" void kernel_launch(void* const* d_in, const int* in_sizes, int n_in,
                              void* d_out, int out_size, void* d_ws, size_t ws_size,
                              hipStream_t stream) {
    const void* query = d_in[0];   // [B,S,DM]  fp32 (auto-detected, bf16-safe)
    const void* W_in  = d_in[1];   // [3TD,DM]
    const void* W_out = d_in[2];   // [DM,TD]
    const void* sin_q = d_in[3];   // [S,HD]
    const void* cos_q = d_in[4];   // [S,HD]   dtype probe
    const void* mask  = d_in[5];   // [B,S] bool, storage auto-detected
    const unsigned int* cosw = (const unsigned int*)cos_q;

    const size_t nQ  = NQ_;   // 4194304
    const size_t nWi = NWI_;  // 3145728
    const size_t nWo = NWO_;  // 1048576

    bf16* qkv  = (bf16*)d_ws;                         // [4096,3072]; later attn out
    bf16* Qh   = qkv + (size_t)4096 * 3072;
    bf16* Kt   = Qh + nQ;                             // tiled+swizzled K
    bf16* qbf  = Kt + nQ;                             // query bf16; later Vt tiles
    bf16* wibf = qbf + nQ;
    bf16* wobf = wibf + nWi;
    int* lengths = (int*)(wobf + nWo);
    bf16* Vt   = qbf;    // alias: qbf dead after gemm1
    bf16* attn = qkv;    // alias: qkv dead after rope_vt

    prep_all<<<NCVT_BLOCKS + B_, 256, 0, stream>>>(
        query, W_in, W_out, qbf, mask, lengths, cosw);

    dim3 g1(3072 / 128, 4096 / 128);
    gemm_nt<<<g1, 256, 0, stream>>>(qbf, wibf, qkv, 4096, 3072, 1024, 0, cosw);

    rope_vt<<<16384 + 1024, 256, 0, stream>>>(qkv, sin_q, cos_q, Qh, Kt, Vt);

    attn_fused<<<512, 256, 0, stream>>>(Qh, Kt, Vt, lengths, attn);

    dim3 g2(1024 / 128, 4096 / 128);
    gemm_nt<<<g2, 256, 0, stream>>>(attn, wobf, d_out, 4096, 1024, 1024, 1, cosw);
}

// Round 11
// 198.991 us; speedup vs baseline: 1.0445x; 1.0445x over previous
//
#include <hip/hip_runtime.h>
#include <hip/hip_bf16.h>

// Problem constants
#define B_ 2
#define S_ 2048
#define DM_ 1024
#define TD_ 1024
#define H_ 16
#define HD_ 64

using bf16 = __hip_bfloat16;
typedef __attribute__((ext_vector_type(8))) short s8v;   // 8 bf16 = one MFMA A/B frag
typedef __attribute__((ext_vector_type(4))) float f4v;   // MFMA C/D frag

__device__ __forceinline__ f4v mfma_bf16(s8v a, s8v b, f4v c) {
    return __builtin_amdgcn_mfma_f32_16x16x32_bf16(a, b, c, 0, 0, 0);
}

// HW packed fp32x2 -> bf16x2 (RNE), single VOP3 instr on CDNA3/4
__device__ __forceinline__ unsigned cvt_pk_bf16(float a, float b) {
    unsigned r;
    asm("v_cvt_pk_bf16_f32 %0, %1, %2" : "=v"(r) : "v"(a), "v"(b));
    return r;
}
__device__ __forceinline__ int2 pack4bf(float a, float b, float c, float d) {
    int2 r;
    r.x = (int)cvt_pk_bf16(a, b);
    r.y = (int)cvt_pk_bf16(c, d);
    return r;
}

// cos_q[0] == 1.0 exactly: fp32 word = 0x3F800000 (low16==0); bf16 pair != 0 low16.
__device__ __forceinline__ bool detect_f32(const unsigned int* __restrict__ cosw) {
    return (cosw[0] & 0xFFFFu) == 0u;
}

__device__ __forceinline__ float ld_f(const void* p, int idx, bool f32) {
    return f32 ? ((const float*)p)[idx]
               : __bfloat162float(((const bf16*)p)[idx]);
}

// async global -> LDS, 16 B per lane (HW: dst = wave-uniform base + lane*16)
__device__ __forceinline__ void gload_lds16(const bf16* g, void* l) {
    __builtin_amdgcn_global_load_lds(
        (const __attribute__((address_space(1))) unsigned int*)(const void*)g,
        (__attribute__((address_space(3))) unsigned int*)l,
        16, 0, 0);
}

#define NQ_  (B_ * S_ * DM_)
#define NWI_ (3 * TD_ * DM_)
#define NWO_ (DM_ * TD_)
#define NCVT_BLOCKS ((NQ_ + NWI_ + NWO_) / 2048)   // 4096

// ---------------------------------------------------------------------------
// Fused prep: blocks [0,4096) convert (query|W_in|W_out) -> bf16;
// blocks 4096..4097 compute lengths[b] from the mask (4-way storage detect).
// ---------------------------------------------------------------------------
__global__ __launch_bounds__(256)
void prep_all(const void* __restrict__ q, const void* __restrict__ wi,
              const void* __restrict__ wo, bf16* __restrict__ dst,
              const void* __restrict__ mask, int* __restrict__ lengths,
              const unsigned int* __restrict__ cosw) {
    const int bid = blockIdx.x;
    if (bid < NCVT_BLOCKS) {
        const bool f32 = detect_f32(cosw);
        int i = (bid * 256 + threadIdx.x) * 8;
        const void* src; int off;
        if (i < NQ_)              { src = q;  off = i; }
        else if (i < NQ_ + NWI_)  { src = wi; off = i - NQ_; }
        else                      { src = wo; off = i - NQ_ - NWI_; }
        if (f32) {
            const float* p = (const float*)src + off;
            float4 x = *reinterpret_cast<const float4*>(p);
            float4 y = *reinterpret_cast<const float4*>(p + 4);
            union { unsigned u[4]; int4 v; } t;
            t.u[0] = cvt_pk_bf16(x.x, x.y);
            t.u[1] = cvt_pk_bf16(x.z, x.w);
            t.u[2] = cvt_pk_bf16(y.x, y.y);
            t.u[3] = cvt_pk_bf16(y.z, y.w);
            *reinterpret_cast<int4*>(dst + i) = t.v;
        } else {
            *reinterpret_cast<int4*>(dst + i) =
                *reinterpret_cast<const int4*>((const bf16*)src + off);
        }
        return;
    }
    // lengths path
    int b = bid - NCVT_BLOCKS;
    unsigned int w0 = ((const unsigned int*)mask)[0];
    int enc;                 // 0=i32, 1=u8, 2=bf16, 3=f32
    if (w0 == 1u) enc = 0;
    else if (w0 == 0x01010101u) enc = 1;
    else if (w0 == 0x3F803F80u) enc = 2;
    else enc = 3;
    int cnt = 0;
    for (int s = threadIdx.x; s < S_; s += 256) {
        int i = b * S_ + s;
        bool v;
        if (enc == 0)      v = ((const int*)mask)[i] != 0;
        else if (enc == 1) v = ((const unsigned char*)mask)[i] != 0;
        else if (enc == 2) v = ((const unsigned short*)mask)[i] != 0;
        else               v = ((const float*)mask)[i] != 0.f;
        cnt += v ? 1 : 0;
    }
    __shared__ int red[256];
    red[threadIdx.x] = cnt;
    __syncthreads();
    for (int off = 128; off > 0; off >>= 1) {
        if (threadIdx.x < off) red[threadIdx.x] += red[threadIdx.x + off];
        __syncthreads();
    }
    if (threadIdx.x == 0) lengths[b] = red[0];
}

// ---------------------------------------------------------------------------
// NT GEMM: C[M][N] = A[M][K]*Bm[N][K]^T. bf16 in, fp32 acc. BK=64,
// global_load_lds width-16, XOR-swizzled LDS. MFMA operands SWAPPED
// (D = Bm_tile * A_tile) so each lane owns 4 consecutive n -> b64/b128 stores.
// c_dyn: 1 -> write detected dtype (fp32 if inputs fp32), 0 -> bf16.
// ---------------------------------------------------------------------------
__global__ __launch_bounds__(256)
void gemm_nt(const bf16* __restrict__ A, const bf16* __restrict__ Bm,
             void* __restrict__ C, int M, int N, int K,
             int c_dyn, const unsigned int* __restrict__ cosw) {
    __shared__ bf16 lds_a[128 * 64];   // 16 KB, [row][chunk^(row&7)]
    __shared__ bf16 lds_b[128 * 64];

    const bool cf32 = c_dyn && detect_f32(cosw);

    const int t = threadIdx.x;
    const int wave = t >> 6, lane = t & 63;
    const int quad = lane >> 4, l16 = lane & 15;
    const int wm = wave >> 1, wn = wave & 1;
    const int m0 = blockIdx.y * 128, n0 = blockIdx.x * 128;
    const int wuni = __builtin_amdgcn_readfirstlane(wave);   // wave-uniform

    f4v acc[4][4];
    #pragma unroll
    for (int i = 0; i < 4; i++)
        #pragma unroll
        for (int j = 0; j < 4; j++)
            acc[i][j] = f4v{0.f, 0.f, 0.f, 0.f};

    for (int k0 = 0; k0 < K; k0 += 64) {
        __syncthreads();                 // prior reads done before restage
        #pragma unroll
        for (int i = 0; i < 4; i++) {
            int ci = i * 256 + t;        // chunk 0..1023 (16B each)
            int row = ci >> 3;
            int csrc = (ci & 7) ^ (row & 7);
            gload_lds16(A + (size_t)(m0 + row) * K + k0 + csrc * 8,
                        (char*)lds_a + i * 4096 + wuni * 1024);
            gload_lds16(Bm + (size_t)(n0 + row) * K + k0 + csrc * 8,
                        (char*)lds_b + i * 4096 + wuni * 1024);
        }
        __syncthreads();                 // drains vmcnt -> staged data visible

        #pragma unroll
        for (int kk = 0; kk < 2; kk++) {
            s8v afr[4], bfr[4];
            #pragma unroll
            for (int mb = 0; mb < 4; mb++) {
                int r = wm * 64 + mb * 16 + l16;
                int ch = (kk * 4 + quad) ^ (l16 & 7);
                afr[mb] = *reinterpret_cast<const s8v*>(&lds_a[r * 64 + ch * 8]);
            }
            #pragma unroll
            for (int nb = 0; nb < 4; nb++) {
                int r = wn * 64 + nb * 16 + l16;
                int ch = (kk * 4 + quad) ^ (l16 & 7);
                bfr[nb] = *reinterpret_cast<const s8v*>(&lds_b[r * 64 + ch * 8]);
            }
            // swapped: D[i=n-in-16][j=m-in-16], lane j=l16, regs i=quad*4+rr
            #pragma unroll
            for (int mb = 0; mb < 4; mb++)
                #pragma unroll
                for (int nb = 0; nb < 4; nb++)
                    acc[mb][nb] = mfma_bf16(bfr[nb], afr[mb], acc[mb][nb]);
        }
    }

    // epilogue: m = m0+wm*64+mb*16+l16 (per lane), n = n0+wn*64+nb*16+quad*4+rr
    #pragma unroll
    for (int mb = 0; mb < 4; mb++) {
        int m = m0 + wm * 64 + mb * 16 + l16;
        #pragma unroll
        for (int nb = 0; nb < 4; nb++) {
            int n = n0 + wn * 64 + nb * 16 + quad * 4;
            f4v v = acc[mb][nb];
            if (cf32) {
                *reinterpret_cast<f4v*>(&((float*)C)[(size_t)m * N + n]) = v;
            } else {
                *reinterpret_cast<int2*>(&((bf16*)C)[(size_t)m * N + n]) =
                    pack4bf(v[0], v[1], v[2], v[3]);
            }
        }
    }
}

// ---------------------------------------------------------------------------
// Fused RoPE + V-transpose (same as round 9).
// ---------------------------------------------------------------------------
__global__ __launch_bounds__(256)
void rope_vt(const bf16* __restrict__ qkv,
             const void* __restrict__ sin_t, const void* __restrict__ cos_t,
             bf16* __restrict__ Qh, bf16* __restrict__ Kt, bf16* __restrict__ Vt) {
    __shared__ bf16 tile[64 * 72];     // used by vt path only
    const int bid = blockIdx.x;
    if (bid < 16384) {
        const bool f32 = detect_f32((const unsigned int*)cos_t);
        int idx = bid * 256 + threadIdx.x;   // B*S*H*HD = 2^22
        int d = idx & 63;
        int h = (idx >> 6) & 15;
        int s = (idx >> 10) & 2047;
        int b = idx >> 21;
        size_t row = (size_t)(b * S_ + s) * 3072;
        int col  = h * 64 + d;
        int colp = h * 64 + ((d + 32) & 63);
        float sgn = (d < 32) ? -1.f : 1.f;
        float cs = ld_f(cos_t, s * 64 + d, f32);
        float sn = ld_f(sin_t, s * 64 + d, f32);
        float q  = __bfloat162float(qkv[row + col]);
        float qp = __bfloat162float(qkv[row + colp]);
        float k  = __bfloat162float(qkv[row + 1024 + col]);
        float kp = __bfloat162float(qkv[row + 1024 + colp]);
        Qh[((size_t)((b * H_ + h) * S_ + s)) * 64 + d] =
            __float2bfloat16((q * cs + sgn * qp * sn) * 0.180336880f);  // 1/8*log2e
        size_t ktile = ((size_t)(b * H_ + h) * 32 + (s >> 6)) * 4096;
        int dp = ((((d >> 3) ^ (s & 7)) << 3) | (d & 7));
        Kt[ktile + (s & 63) * 64 + dp] = __float2bfloat16(k * cs + sgn * kp * sn);
        return;
    }
    // V-transpose path
    const int vid = bid - 16384;       // 0..1023
    const int sb = vid & 31, h = (vid >> 5) & 15, b = vid >> 9;
    const int t = threadIdx.x;
    #pragma unroll
    for (int i = 0; i < 2; i++) {
        int id = i * 256 + t;          // 0..511
        int row = id >> 3, c = id & 7;
        *reinterpret_cast<int4*>(&tile[row * 72 + c * 8]) =
            *reinterpret_cast<const int4*>(
                qkv + (size_t)(b * S_ + sb * 64 + row) * 3072 + 2048 + h * 64 + c * 8);
    }
    __syncthreads();
    const size_t tb = ((size_t)(b * H_ + h) * 32 + sb) * 4096;
    #pragma unroll
    for (int i = 0; i < 2; i++) {
        int id = i * 256 + t;
        int d = id >> 3, kc = id & 7;  // kc = 8-key chunk
        union { short s[8]; int4 v; } u;
        #pragma unroll
        for (int e = 0; e < 8; e++)
            u.s[e] = reinterpret_cast<const short*>(tile)[(kc * 8 + e) * 72 + d];
        *reinterpret_cast<int4*>(Vt + tb + d * 64 + ((kc ^ (d & 7)) * 8)) = u.v;
    }
}

// ---------------------------------------------------------------------------
// Flash attention v8 = r9 structure + 2 K-tiles per barrier.
// 512 blocks; block handles qb = p (pass 0) and 31-p (pass 1) SEQUENTIALLY
// (uniform 33 tiles total). Ring-4 K and V LDS slots (slot = tile & 3).
// Super-iter j covers tiles 2j, 2j+1 with ONE barrier; staging schedule
// (hazard-checked against the ring): at j stage K[2j+2], K[2j+3],
// V[2j+1], V[2j+2]; prologue stages K[0], K[1], V[0].
// Depth-2 tile pipeline exactly as r9: S[t]; process(t-1); 1 lgkm-local
// P round trip per tile. XCD-clustered decode (bid&7 = XCD).
// ---------------------------------------------------------------------------
__global__ __launch_bounds__(256)
void attn_fused(const bf16* __restrict__ Qh, const bf16* __restrict__ Kt,
                const bf16* __restrict__ Vt, const int* __restrict__ lengths,
                bf16* __restrict__ out) {
    __shared__ bf16 k_buf[4 * 4096];   // ring-4 K tile slots (32 KB)
    __shared__ bf16 v_buf[4 * 4096];   // ring-4 V tile slots (32 KB)
    __shared__ bf16 lds_p[4 * 16 * 72];// per-wave P tile (9 KB)

    const int t = threadIdx.x, wave = t >> 6, lane = t & 63;
    const int quad = lane >> 4, l16 = lane & 15;
    // XCD-clustered decode: 512 blocks, 64 slots/XCD = 4 bh x 16 pairs
    const int bid = blockIdx.x;
    const int slot = bid >> 3;                    // 0..63
    const int bh = (bid & 7) * 4 + (slot >> 4);   // all of a bh on one XCD
    const int p = slot & 15;                      // pair index
    const int b = bh >> 4, h = bh & 15;

    const size_t hb = (size_t)bh * S_ * 64;          // Qh base
    const bf16* Ktp = Kt + (size_t)bh * 32 * 4096;   // tile array base
    const bf16* Vtp = Vt + (size_t)bh * 32 * 4096;
    const int wuni = __builtin_amdgcn_readfirstlane(wave);
    int len_raw = lengths[b];
    const int len_b = len_raw < 1 ? 1 : (len_raw > S_ ? S_ : len_raw);
    const int nkt_len = (len_b + 63) >> 6;

    auto stageK = [&](int x) {
        const bf16* src = Ktp + (size_t)x * 4096;
        char* dstb = (char*)k_buf + (x & 3) * 8192;
        #pragma unroll
        for (int i = 0; i < 2; i++) {
            int ci = i * 256 + t;
            gload_lds16(src + ci * 8, dstb + i * 4096 + wuni * 1024);
        }
    };
    auto stageV = [&](int x) {
        const bf16* src = Vtp + (size_t)x * 4096;
        char* dstb = (char*)v_buf + (x & 3) * 8192;
        #pragma unroll
        for (int i = 0; i < 2; i++) {
            int ci = i * 256 + t;
            gload_lds16(src + ci * 8, dstb + i * 4096 + wuni * 1024);
        }
    };

    #pragma unroll
    for (int pass = 0; pass < 2; pass++) {
        const int qb = pass ? (31 - p) : p;
        const int qbase = qb * 64;
        const int qrow_g = qbase + wave * 16 + l16;   // this lane's q-row
        const int kmax = (qrow_g < len_b - 1) ? qrow_g : (len_b - 1);

        s8v qf[2];
        {
            const bf16* qptr = Qh + hb + (size_t)qrow_g * 64 + quad * 8;
            qf[0] = *reinterpret_cast<const s8v*>(qptr);
            qf[1] = *reinterpret_cast<const s8v*>(qptr + 32);
        }

        f4v o_acc[4];
        #pragma unroll
        for (int a = 0; a < 4; a++) o_acc[a] = f4v{0.f, 0.f, 0.f, 0.f};
        float l_sum = 0.f;

        const int nkt = (qb + 1) < nkt_len ? (qb + 1) : nkt_len;

        f4v s_prev[4];
        // exp + P pack + PV for tile pt (s_prev holds S^T[pt])
        auto process_tile = [&](int pt) {
            const bf16* vb = v_buf + (pt & 3) * 4096;
            const int pbase = pt * 64;
            const bool tail = (pt == qb) || (pbase + 64 > len_b);  // uniform
            #pragma unroll
            for (int a = 0; a < 4; a++) {
                float e0[4];
                #pragma unroll
                for (int r = 0; r < 4; r++) {
                    float e = __builtin_amdgcn_exp2f(s_prev[a][r]);
                    if (tail) {
                        int key = pbase + a * 16 + quad * 4 + r;
                        e = (key <= kmax) ? e : 0.f;
                    }
                    e0[r] = e;
                    l_sum += e;
                }
                *reinterpret_cast<int2*>(
                    &lds_p[(wave * 16 + l16) * 72 + a * 16 + quad * 4]) =
                    pack4bf(e0[0], e0[1], e0[2], e0[3]);
            }
            // wave-local: P writes -> P reads (lds_p region is per-wave)
            asm volatile("s_waitcnt lgkmcnt(0)" ::: "memory");
            #pragma unroll
            for (int kk = 0; kk < 2; kk++) {
                s8v pf = *reinterpret_cast<const s8v*>(
                    &lds_p[(wave * 16 + l16) * 72 + kk * 32 + quad * 8]);
                #pragma unroll
                for (int a = 0; a < 4; a++) {
                    int ch = (kk * 4 + quad) ^ (l16 & 7);
                    s8v vf = *reinterpret_cast<const s8v*>(
                        &vb[(a * 16 + l16) * 64 + ch * 8]);
                    o_acc[a] = mfma_bf16(vf, pf, o_acc[a]);
                }
            }
        };
        auto smfma = [&](int x, f4v* sd) {
            const bf16* kb = k_buf + (x & 3) * 4096;
            #pragma unroll
            for (int kk = 0; kk < 2; kk++) {
                #pragma unroll
                for (int a = 0; a < 4; a++) {
                    int ch = (kk * 4 + quad) ^ (l16 & 7);
                    s8v kf = *reinterpret_cast<const s8v*>(
                        &kb[(a * 16 + l16) * 64 + ch * 8]);
                    sd[a] = mfma_bf16(kf, qf[kk], sd[a]);
                }
            }
        };

        __syncthreads();   // prior pass's LDS reads done before restaging
        // prologue: K[0], K[1], V[0]
        stageK(0);
        if (1 < nkt) stageK(1);
        stageV(0);
        __syncthreads();   // drains vmcnt -> prologue tiles resident

        const int n2 = (nkt + 1) >> 1;
        for (int j = 0; j < n2; j++) {
            const int t0 = 2 * j, t1 = t0 + 1;
            // stage-ahead (ring-safe schedule; all guarded)
            if (t0 + 2 < nkt) stageK(t0 + 2);
            if (t1 + 2 < nkt) stageK(t1 + 2);
            if (t0 + 1 < nkt) stageV(t0 + 1);
            if (t0 + 2 < nkt) stageV(t0 + 2);

            // tile t0
            f4v sn[4];
            #pragma unroll
            for (int a = 0; a < 4; a++) sn[a] = f4v{0.f, 0.f, 0.f, 0.f};
            smfma(t0, sn);
            if (j > 0) process_tile(t0 - 1);
            #pragma unroll
            for (int a = 0; a < 4; a++) s_prev[a] = sn[a];

            // tile t1
            if (t1 < nkt) {
                f4v sn2[4];
                #pragma unroll
                for (int a = 0; a < 4; a++) sn2[a] = f4v{0.f, 0.f, 0.f, 0.f};
                smfma(t1, sn2);
                process_tile(t0);
                #pragma unroll
                for (int a = 0; a < 4; a++) s_prev[a] = sn2[a];
            }

            __syncthreads();   // staged tiles resident; slot reads complete
        }
        // drain: last tile
        process_tile(nkt - 1);

        // reduce l across the 4 quads sharing this q-row, then b64 epilogue
        l_sum += __shfl_xor(l_sum, 16);
        l_sum += __shfl_xor(l_sum, 32);
        float inv_l = 1.f / l_sum;
        size_t orow = ((size_t)(b * S_ + qrow_g)) * TD_ + h * 64;
        #pragma unroll
        for (int a = 0; a < 4; a++) {
            *reinterpret_cast<int2*>(&out[orow + a * 16 + quad * 4]) =
                pack4bf(o_acc[a][0] * inv_l, o_acc[a][1] * inv_l,
                        o_acc[a][2] * inv_l, o_acc[a][3] * inv_l);
        }
    }
}

// ---------------------------------------------------------------------------
extern "C" void kernel_launch(void* const* d_in, const int* in_sizes, int n_in,
                              void* d_out, int out_size, void* d_ws, size_t ws_size,
                              hipStream_t stream) {
    const void* query = d_in[0];   // [B,S,DM]  fp32 (auto-detected, bf16-safe)
    const void* W_in  = d_in[1];   // [3TD,DM]
    const void* W_out = d_in[2];   // [DM,TD]
    const void* sin_q = d_in[3];   // [S,HD]
    const void* cos_q = d_in[4];   // [S,HD]   dtype probe
    const void* mask  = d_in[5];   // [B,S] bool, storage auto-detected
    const unsigned int* cosw = (const unsigned int*)cos_q;

    const size_t nQ  = NQ_;   // 4194304
    const size_t nWi = NWI_;  // 3145728
    const size_t nWo = NWO_;  // 1048576

    bf16* qkv  = (bf16*)d_ws;                         // [4096,3072]; later attn out
    bf16* Qh   = qkv + (size_t)4096 * 3072;
    bf16* Kt   = Qh + nQ;                             // tiled+swizzled K
    bf16* qbf  = Kt + nQ;                             // query bf16; later Vt tiles
    bf16* wibf = qbf + nQ;
    bf16* wobf = wibf + nWi;
    int* lengths = (int*)(wobf + nWo);
    bf16* Vt   = qbf;    // alias: qbf dead after gemm1
    bf16* attn = qkv;    // alias: qkv dead after rope_vt

    prep_all<<<NCVT_BLOCKS + B_, 256, 0, stream>>>(
        query, W_in, W_out, qbf, mask, lengths, cosw);

    dim3 g1(3072 / 128, 4096 / 128);
    gemm_nt<<<g1, 256, 0, stream>>>(qbf, wibf, qkv, 4096, 3072, 1024, 0, cosw);

    rope_vt<<<16384 + 1024, 256, 0, stream>>>(qkv, sin_q, cos_q, Qh, Kt, Vt);

    attn_fused<<<512, 256, 0, stream>>>(Qh, Kt, Vt, lengths, attn);

    dim3 g2(1024 / 128, 4096 / 128);
    gemm_nt<<<g2, 256, 0, stream>>>(attn, wobf, d_out, 4096, 1024, 1024, 1, cosw);
}

// Round 12
// 197.519 us; speedup vs baseline: 1.0523x; 1.0075x over previous
//
#include <hip/hip_runtime.h>
#include <hip/hip_bf16.h>

// Problem constants
#define B_ 2
#define S_ 2048
#define DM_ 1024
#define TD_ 1024
#define H_ 16
#define HD_ 64

using bf16 = __hip_bfloat16;
typedef __attribute__((ext_vector_type(8))) short s8v;   // 8 bf16 = one MFMA A/B frag
typedef __attribute__((ext_vector_type(4))) float f4v;   // MFMA C/D frag

__device__ __forceinline__ f4v mfma_bf16(s8v a, s8v b, f4v c) {
    return __builtin_amdgcn_mfma_f32_16x16x32_bf16(a, b, c, 0, 0, 0);
}

// HW packed fp32x2 -> bf16x2 (RNE), single VOP3 instr on CDNA3/4
__device__ __forceinline__ unsigned cvt_pk_bf16(float a, float b) {
    unsigned r;
    asm("v_cvt_pk_bf16_f32 %0, %1, %2" : "=v"(r) : "v"(a), "v"(b));
    return r;
}
__device__ __forceinline__ int2 pack4bf(float a, float b, float c, float d) {
    int2 r;
    r.x = (int)cvt_pk_bf16(a, b);
    r.y = (int)cvt_pk_bf16(c, d);
    return r;
}

// cos_q[0] == 1.0 exactly: fp32 word = 0x3F800000 (low16==0); bf16 pair != 0 low16.
__device__ __forceinline__ bool detect_f32(const unsigned int* __restrict__ cosw) {
    return (cosw[0] & 0xFFFFu) == 0u;
}

__device__ __forceinline__ float ld_f(const void* p, int idx, bool f32) {
    return f32 ? ((const float*)p)[idx]
               : __bfloat162float(((const bf16*)p)[idx]);
}

// async global -> LDS, 16 B per lane (HW: dst = wave-uniform base + lane*16)
__device__ __forceinline__ void gload_lds16(const bf16* g, void* l) {
    __builtin_amdgcn_global_load_lds(
        (const __attribute__((address_space(1))) unsigned int*)(const void*)g,
        (__attribute__((address_space(3))) unsigned int*)l,
        16, 0, 0);
}

#define NQ_  (B_ * S_ * DM_)
#define NWI_ (3 * TD_ * DM_)
#define NWO_ (DM_ * TD_)
#define NCVT_BLOCKS ((NQ_ + NWI_ + NWO_) / 2048)   // 4096

// ---------------------------------------------------------------------------
// Fused prep: blocks [0,4096) convert (query|W_in|W_out) -> bf16;
// blocks 4096..4097 compute lengths[b] from the mask (4-way storage detect).
// ---------------------------------------------------------------------------
__global__ __launch_bounds__(256)
void prep_all(const void* __restrict__ q, const void* __restrict__ wi,
              const void* __restrict__ wo, bf16* __restrict__ dst,
              const void* __restrict__ mask, int* __restrict__ lengths,
              const unsigned int* __restrict__ cosw) {
    const int bid = blockIdx.x;
    if (bid < NCVT_BLOCKS) {
        const bool f32 = detect_f32(cosw);
        int i = (bid * 256 + threadIdx.x) * 8;
        const void* src; int off;
        if (i < NQ_)              { src = q;  off = i; }
        else if (i < NQ_ + NWI_)  { src = wi; off = i - NQ_; }
        else                      { src = wo; off = i - NQ_ - NWI_; }
        if (f32) {
            const float* p = (const float*)src + off;
            float4 x = *reinterpret_cast<const float4*>(p);
            float4 y = *reinterpret_cast<const float4*>(p + 4);
            union { unsigned u[4]; int4 v; } t;
            t.u[0] = cvt_pk_bf16(x.x, x.y);
            t.u[1] = cvt_pk_bf16(x.z, x.w);
            t.u[2] = cvt_pk_bf16(y.x, y.y);
            t.u[3] = cvt_pk_bf16(y.z, y.w);
            *reinterpret_cast<int4*>(dst + i) = t.v;
        } else {
            *reinterpret_cast<int4*>(dst + i) =
                *reinterpret_cast<const int4*>((const bf16*)src + off);
        }
        return;
    }
    // lengths path
    int b = bid - NCVT_BLOCKS;
    unsigned int w0 = ((const unsigned int*)mask)[0];
    int enc;                 // 0=i32, 1=u8, 2=bf16, 3=f32
    if (w0 == 1u) enc = 0;
    else if (w0 == 0x01010101u) enc = 1;
    else if (w0 == 0x3F803F80u) enc = 2;
    else enc = 3;
    int cnt = 0;
    for (int s = threadIdx.x; s < S_; s += 256) {
        int i = b * S_ + s;
        bool v;
        if (enc == 0)      v = ((const int*)mask)[i] != 0;
        else if (enc == 1) v = ((const unsigned char*)mask)[i] != 0;
        else if (enc == 2) v = ((const unsigned short*)mask)[i] != 0;
        else               v = ((const float*)mask)[i] != 0.f;
        cnt += v ? 1 : 0;
    }
    __shared__ int red[256];
    red[threadIdx.x] = cnt;
    __syncthreads();
    for (int off = 128; off > 0; off >>= 1) {
        if (threadIdx.x < off) red[threadIdx.x] += red[threadIdx.x + off];
        __syncthreads();
    }
    if (threadIdx.x == 0) lengths[b] = red[0];
}

// ---------------------------------------------------------------------------
// NT GEMM: C[M][N] = A[M][K]*Bm[N][K]^T. bf16 in, fp32 acc. BK=64,
// global_load_lds width-16, XOR-swizzled LDS. MFMA operands SWAPPED
// (D = Bm_tile * A_tile) so each lane owns 4 consecutive n -> b64/b128 stores.
// c_dyn: 1 -> write detected dtype (fp32 if inputs fp32), 0 -> bf16.
// ---------------------------------------------------------------------------
__global__ __launch_bounds__(256)
void gemm_nt(const bf16* __restrict__ A, const bf16* __restrict__ Bm,
             void* __restrict__ C, int M, int N, int K,
             int c_dyn, const unsigned int* __restrict__ cosw) {
    __shared__ bf16 lds_a[128 * 64];   // 16 KB, [row][chunk^(row&7)]
    __shared__ bf16 lds_b[128 * 64];

    const bool cf32 = c_dyn && detect_f32(cosw);

    const int t = threadIdx.x;
    const int wave = t >> 6, lane = t & 63;
    const int quad = lane >> 4, l16 = lane & 15;
    const int wm = wave >> 1, wn = wave & 1;
    const int m0 = blockIdx.y * 128, n0 = blockIdx.x * 128;
    const int wuni = __builtin_amdgcn_readfirstlane(wave);   // wave-uniform

    f4v acc[4][4];
    #pragma unroll
    for (int i = 0; i < 4; i++)
        #pragma unroll
        for (int j = 0; j < 4; j++)
            acc[i][j] = f4v{0.f, 0.f, 0.f, 0.f};

    for (int k0 = 0; k0 < K; k0 += 64) {
        __syncthreads();                 // prior reads done before restage
        #pragma unroll
        for (int i = 0; i < 4; i++) {
            int ci = i * 256 + t;        // chunk 0..1023 (16B each)
            int row = ci >> 3;
            int csrc = (ci & 7) ^ (row & 7);
            gload_lds16(A + (size_t)(m0 + row) * K + k0 + csrc * 8,
                        (char*)lds_a + i * 4096 + wuni * 1024);
            gload_lds16(Bm + (size_t)(n0 + row) * K + k0 + csrc * 8,
                        (char*)lds_b + i * 4096 + wuni * 1024);
        }
        __syncthreads();                 // drains vmcnt -> staged data visible

        #pragma unroll
        for (int kk = 0; kk < 2; kk++) {
            s8v afr[4], bfr[4];
            #pragma unroll
            for (int mb = 0; mb < 4; mb++) {
                int r = wm * 64 + mb * 16 + l16;
                int ch = (kk * 4 + quad) ^ (l16 & 7);
                afr[mb] = *reinterpret_cast<const s8v*>(&lds_a[r * 64 + ch * 8]);
            }
            #pragma unroll
            for (int nb = 0; nb < 4; nb++) {
                int r = wn * 64 + nb * 16 + l16;
                int ch = (kk * 4 + quad) ^ (l16 & 7);
                bfr[nb] = *reinterpret_cast<const s8v*>(&lds_b[r * 64 + ch * 8]);
            }
            // swapped: D[i=n-in-16][j=m-in-16], lane j=l16, regs i=quad*4+rr
            #pragma unroll
            for (int mb = 0; mb < 4; mb++)
                #pragma unroll
                for (int nb = 0; nb < 4; nb++)
                    acc[mb][nb] = mfma_bf16(bfr[nb], afr[mb], acc[mb][nb]);
        }
    }

    // epilogue: m = m0+wm*64+mb*16+l16 (per lane), n = n0+wn*64+nb*16+quad*4+rr
    #pragma unroll
    for (int mb = 0; mb < 4; mb++) {
        int m = m0 + wm * 64 + mb * 16 + l16;
        #pragma unroll
        for (int nb = 0; nb < 4; nb++) {
            int n = n0 + wn * 64 + nb * 16 + quad * 4;
            f4v v = acc[mb][nb];
            if (cf32) {
                *reinterpret_cast<f4v*>(&((float*)C)[(size_t)m * N + n]) = v;
            } else {
                *reinterpret_cast<int2*>(&((bf16*)C)[(size_t)m * N + n]) =
                    pack4bf(v[0], v[1], v[2], v[3]);
            }
        }
    }
}

// ---------------------------------------------------------------------------
// Fused RoPE + V-transpose (same as round 9).
// ---------------------------------------------------------------------------
__global__ __launch_bounds__(256)
void rope_vt(const bf16* __restrict__ qkv,
             const void* __restrict__ sin_t, const void* __restrict__ cos_t,
             bf16* __restrict__ Qh, bf16* __restrict__ Kt, bf16* __restrict__ Vt) {
    __shared__ bf16 tile[64 * 72];     // used by vt path only
    const int bid = blockIdx.x;
    if (bid < 16384) {
        const bool f32 = detect_f32((const unsigned int*)cos_t);
        int idx = bid * 256 + threadIdx.x;   // B*S*H*HD = 2^22
        int d = idx & 63;
        int h = (idx >> 6) & 15;
        int s = (idx >> 10) & 2047;
        int b = idx >> 21;
        size_t row = (size_t)(b * S_ + s) * 3072;
        int col  = h * 64 + d;
        int colp = h * 64 + ((d + 32) & 63);
        float sgn = (d < 32) ? -1.f : 1.f;
        float cs = ld_f(cos_t, s * 64 + d, f32);
        float sn = ld_f(sin_t, s * 64 + d, f32);
        float q  = __bfloat162float(qkv[row + col]);
        float qp = __bfloat162float(qkv[row + colp]);
        float k  = __bfloat162float(qkv[row + 1024 + col]);
        float kp = __bfloat162float(qkv[row + 1024 + colp]);
        Qh[((size_t)((b * H_ + h) * S_ + s)) * 64 + d] =
            __float2bfloat16((q * cs + sgn * qp * sn) * 0.180336880f);  // 1/8*log2e
        size_t ktile = ((size_t)(b * H_ + h) * 32 + (s >> 6)) * 4096;
        int dp = ((((d >> 3) ^ (s & 7)) << 3) | (d & 7));
        Kt[ktile + (s & 63) * 64 + dp] = __float2bfloat16(k * cs + sgn * kp * sn);
        return;
    }
    // V-transpose path
    const int vid = bid - 16384;       // 0..1023
    const int sb = vid & 31, h = (vid >> 5) & 15, b = vid >> 9;
    const int t = threadIdx.x;
    #pragma unroll
    for (int i = 0; i < 2; i++) {
        int id = i * 256 + t;          // 0..511
        int row = id >> 3, c = id & 7;
        *reinterpret_cast<int4*>(&tile[row * 72 + c * 8]) =
            *reinterpret_cast<const int4*>(
                qkv + (size_t)(b * S_ + sb * 64 + row) * 3072 + 2048 + h * 64 + c * 8);
    }
    __syncthreads();
    const size_t tb = ((size_t)(b * H_ + h) * 32 + sb) * 4096;
    #pragma unroll
    for (int i = 0; i < 2; i++) {
        int id = i * 256 + t;
        int d = id >> 3, kc = id & 7;  // kc = 8-key chunk
        union { short s[8]; int4 v; } u;
        #pragma unroll
        for (int e = 0; e < 8; e++)
            u.s[e] = reinterpret_cast<const short*>(tile)[(kc * 8 + e) * 72 + d];
        *reinterpret_cast<int4*>(Vt + tb + d * 64 + ((kc ^ (d & 7)) * 8)) = u.v;
    }
}

// ---------------------------------------------------------------------------
// Flash attention v9: 512-thread blocks (8 waves). Waves 0-3 own q-tile 2g,
// waves 4-7 own q-tile 2g+1; K/V staged ONCE per block and shared. Each wave
// runs the r9 depth-2 per-wave pipeline unchanged (S[kt]; exp/pack/PV[kt-1];
// wave-local lgkm P round trip). Block span = min(2g+2, nkt_len) tiles,
// 1 barrier/tile. Staging: one global_load_lds per thread per tile.
// CU pairing: bid & bid+256 (same XCD via &7) carry g and 15-g -> span sum 34.
// ---------------------------------------------------------------------------
__global__ __launch_bounds__(512)
void attn_fused(const bf16* __restrict__ Qh, const bf16* __restrict__ Kt,
                const bf16* __restrict__ Vt, const int* __restrict__ lengths,
                bf16* __restrict__ out) {
    __shared__ bf16 k_buf[2 * 4096];   // dbuf K tiles  (16 KB)
    __shared__ bf16 v_buf[2 * 4096];   // dbuf V tiles  (16 KB)
    __shared__ bf16 lds_p[8 * 16 * 72];// per-wave P regions (18 KB)

    const int t = threadIdx.x, wave = t >> 6, lane = t & 63;
    const int quad = lane >> 4, l16 = lane & 15;
    const int grp = wave >> 2;          // 0 -> qb=2g, 1 -> qb=2g+1
    const int wq = wave & 3;            // wave-in-group -> 16-row band

    // decode: xcd = bid&7; lo half (bid<256): g = 0..7; hi half: g = 15..8
    const int bid = blockIdx.x;
    const int xcd = bid & 7;
    int g, bh;
    if (bid < 256) {
        int r = bid >> 3;               // 0..31
        bh = xcd * 4 + (r & 3);
        g = r >> 2;                     // 0..7
    } else {
        int r = (bid - 256) >> 3;
        bh = xcd * 4 + (r & 3);
        g = 15 - (r >> 2);              // 15..8
    }
    const int qb = 2 * g + grp;
    const int b = bh >> 4, h = bh & 15;

    const size_t hb = (size_t)bh * S_ * 64;          // Qh base
    const bf16* Ktp = Kt + (size_t)bh * 32 * 4096;   // tile array base
    const bf16* Vtp = Vt + (size_t)bh * 32 * 4096;
    const int wuni = __builtin_amdgcn_readfirstlane(wave);
    int len_raw = lengths[b];
    const int len_b = len_raw < 1 ? 1 : (len_raw > S_ ? S_ : len_raw);
    const int nkt_len = (len_b + 63) >> 6;

    const int nkt_w = (qb + 1) < nkt_len ? (qb + 1) : nkt_len;      // wave span
    const int nkt   = (2 * g + 2) < nkt_len ? (2 * g + 2) : nkt_len;// block span

    const int qrow_g = qb * 64 + wq * 16 + l16;      // this lane's q-row
    const int kmax = (qrow_g < len_b - 1) ? qrow_g : (len_b - 1);

    s8v qf[2];
    {
        const bf16* qptr = Qh + hb + (size_t)qrow_g * 64 + quad * 8;
        qf[0] = *reinterpret_cast<const s8v*>(qptr);
        qf[1] = *reinterpret_cast<const s8v*>(qptr + 32);
    }

    f4v o_acc[4];
    #pragma unroll
    for (int a = 0; a < 4; a++) o_acc[a] = f4v{0.f, 0.f, 0.f, 0.f};
    float l_sum = 0.f;

    // one 16B chunk per thread per tile (512 threads x 16 B = 8 KB tile)
    auto stageK = [&](int x) {
        gload_lds16(Ktp + (size_t)x * 4096 + t * 8,
                    (char*)k_buf + (x & 1) * 8192 + wuni * 1024);
    };
    auto stageV = [&](int x) {
        gload_lds16(Vtp + (size_t)x * 4096 + t * 8,
                    (char*)v_buf + (x & 1) * 8192 + wuni * 1024);
    };

    f4v s_prev[4];
    // exp + P pack + PV for tile pt (s_prev holds S^T[pt]); wave-local
    auto process_tile = [&](int pt) {
        const bf16* vb = v_buf + (pt & 1) * 4096;
        const int pbase = pt * 64;
        const bool tail = (pt == qb) || (pbase + 64 > len_b);  // wave-uniform
        #pragma unroll
        for (int a = 0; a < 4; a++) {
            float e0[4];
            #pragma unroll
            for (int r = 0; r < 4; r++) {
                float e = __builtin_amdgcn_exp2f(s_prev[a][r]);
                if (tail) {
                    int key = pbase + a * 16 + quad * 4 + r;
                    e = (key <= kmax) ? e : 0.f;
                }
                e0[r] = e;
                l_sum += e;
            }
            *reinterpret_cast<int2*>(
                &lds_p[(wave * 16 + l16) * 72 + a * 16 + quad * 4]) =
                pack4bf(e0[0], e0[1], e0[2], e0[3]);
        }
        // wave-local: P writes -> P reads (lds_p region is per-wave)
        asm volatile("s_waitcnt lgkmcnt(0)" ::: "memory");
        #pragma unroll
        for (int kk = 0; kk < 2; kk++) {
            s8v pf = *reinterpret_cast<const s8v*>(
                &lds_p[(wave * 16 + l16) * 72 + kk * 32 + quad * 8]);
            #pragma unroll
            for (int a = 0; a < 4; a++) {
                int ch = (kk * 4 + quad) ^ (l16 & 7);
                s8v vf = *reinterpret_cast<const s8v*>(
                    &vb[(a * 16 + l16) * 64 + ch * 8]);
                o_acc[a] = mfma_bf16(vf, pf, o_acc[a]);
            }
        }
    };

    // prologue: stage K[0]
    stageK(0);
    __syncthreads();   // K[0] resident (drains vmcnt)

    for (int kt = 0; kt < nkt; kt++) {
        // stage V[kt] -> vbuf[kt&1]; K[kt+1] -> kbuf[(kt+1)&1]  (all threads)
        stageV(kt);
        if (kt + 1 < nkt) stageK(kt + 1);

        // S^T[kt] (only waves whose span covers kt)
        const bool act = (kt < nkt_w);
        f4v sn[4];
        if (act) {
            const bf16* kb = k_buf + (kt & 1) * 4096;
            #pragma unroll
            for (int a = 0; a < 4; a++) sn[a] = f4v{0.f, 0.f, 0.f, 0.f};
            #pragma unroll
            for (int kk = 0; kk < 2; kk++) {
                #pragma unroll
                for (int a = 0; a < 4; a++) {
                    int ch = (kk * 4 + quad) ^ (l16 & 7);
                    s8v kf = *reinterpret_cast<const s8v*>(
                        &kb[(a * 16 + l16) * 64 + ch * 8]);
                    sn[a] = mfma_bf16(kf, qf[kk], sn[a]);
                }
            }
        }

        // overlap: previous tile's exp/pack/PV under this tile's S-MFMA
        if (kt >= 1 && (kt - 1) < nkt_w) process_tile(kt - 1);

        if (act) {
            #pragma unroll
            for (int a = 0; a < 4; a++) s_prev[a] = sn[a];
        }

        __syncthreads();   // staged tiles resident; slot reads complete
    }
    // drain: waves whose span equals the block span still owe the last tile
    if (nkt_w == nkt) process_tile(nkt_w - 1);

    // reduce l across the 4 quads sharing this q-row, then b64 epilogue
    l_sum += __shfl_xor(l_sum, 16);
    l_sum += __shfl_xor(l_sum, 32);
    float inv_l = 1.f / l_sum;
    size_t orow = ((size_t)(b * S_ + qrow_g)) * TD_ + h * 64;
    #pragma unroll
    for (int a = 0; a < 4; a++) {
        *reinterpret_cast<int2*>(&out[orow + a * 16 + quad * 4]) =
            pack4bf(o_acc[a][0] * inv_l, o_acc[a][1] * inv_l,
                    o_acc[a][2] * inv_l, o_acc[a][3] * inv_l);
    }
}

// ---------------------------------------------------------------------------
extern "C" void kernel_launch(void* const* d_in, const int* in_sizes, int n_in,
                              void* d_out, int out_size, void* d_ws, size_t ws_size,
                              hipStream_t stream) {
    const void* query = d_in[0];   // [B,S,DM]  fp32 (auto-detected, bf16-safe)
    const void* W_in  = d_in[1];   // [3TD,DM]
    const void* W_out = d_in[2];   // [DM,TD]
    const void* sin_q = d_in[3];   // [S,HD]
    const void* cos_q = d_in[4];   // [S,HD]   dtype probe
    const void* mask  = d_in[5];   // [B,S] bool, storage auto-detected
    const unsigned int* cosw = (const unsigned int*)cos_q;

    const size_t nQ  = NQ_;   // 4194304
    const size_t nWi = NWI_;  // 3145728
    const size_t nWo = NWO_;  // 1048576

    bf16* qkv  = (bf16*)d_ws;                         // [4096,3072]; later attn out
    bf16* Qh   = qkv + (size_t)4096 * 3072;
    bf16* Kt   = Qh + nQ;                             // tiled+swizzled K
    bf16* qbf  = Kt + nQ;                             // query bf16; later Vt tiles
    bf16* wibf = qbf + nQ;
    bf16* wobf = wibf + nWi;
    int* lengths = (int*)(wobf + nWo);
    bf16* Vt   = qbf;    // alias: qbf dead after gemm1
    bf16* attn = qkv;    // alias: qkv dead after rope_vt

    prep_all<<<NCVT_BLOCKS + B_, 256, 0, stream>>>(
        query, W_in, W_out, qbf, mask, lengths, cosw);

    dim3 g1(3072 / 128, 4096 / 128);
    gemm_nt<<<g1, 256, 0, stream>>>(qbf, wibf, qkv, 4096, 3072, 1024, 0, cosw);

    rope_vt<<<16384 + 1024, 256, 0, stream>>>(qkv, sin_q, cos_q, Qh, Kt, Vt);

    attn_fused<<<512, 512, 0, stream>>>(Qh, Kt, Vt, lengths, attn);

    dim3 g2(1024 / 128, 4096 / 128);
    gemm_nt<<<g2, 256, 0, stream>>>(attn, wobf, d_out, 4096, 1024, 1024, 1, cosw);
}